// Round 3
// baseline (522.755 us; speedup 1.0000x reference)
//
#include <hip/hip_runtime.h>
#include <stdint.h>

#define NB 32768
#define NPASS 4
#define FULL27 0x07FFFFFFu

// Fused kernel: one wave (64 threads) handles 64 puzzles.
// LDS bit-pool: 64 puzzles x 729 bits = 46656 bits = 1458 dwords (+2 pad).
// Flat bit i of the pool == input float [blockBase*729 + i] != 0.
// Puzzle p (lane p) owns bits [p*729, (p+1)*729); word q = bits p*729+q*27 .. +26.
// Word (d*3+b): digit d, band b, bit (r*9+c). BOX k: 0x1C0E07<<3k; COL c: 0x40201<<c.

__global__ __launch_bounds__(64, 1)
void sudoku_fused_kernel(const uint32_t* __restrict__ in, float* __restrict__ out,
                         float* __restrict__ solved) {
    __shared__ uint32_t pool[1460];
    const int lane = threadIdx.x;
    const int blockBase = blockIdx.x * 64;                 // first puzzle of this block
    const uint32_t* src = in + (size_t)blockBase * 729;
    float* dst = out + (size_t)blockBase * 729;

    // ---------------- PACK: coalesced loads -> ballot -> LDS bit pool ----------------
    #pragma unroll 9
    for (int i = 0; i < 729; ++i) {
        uint32_t v = src[i * 64 + lane];
        unsigned long long mask = __ballot(v != 0u);       // bit L = lane L's float != 0
        if (lane < 2) {
            uint32_t piece = lane ? (uint32_t)(mask >> 32) : (uint32_t)mask;
            pool[2 * i + lane] = piece;
        }
    }
    __syncthreads();

    // ---------------- EXTRACT: 27 words for this lane's puzzle ----------------
    uint32_t bd[9][3];
    {
        const int base = lane * 729;
        #pragma unroll
        for (int q = 0; q < 27; ++q) {
            int bit = base + q * 27;
            int di = bit >> 5;
            int sh = bit & 31;
            uint64_t both = (uint64_t)pool[di] | ((uint64_t)pool[di + 1] << 32);
            bd[q / 3][q % 3] = (uint32_t)(both >> sh) & FULL27;
        }
    }

    // ---------------- SOLVE (identical to validated round-2 logic) ----------------
    for (int pass = 0; pass < NPASS; ++pass) {
        // ---------- filter 'box': solved cell eliminates digit from rest of box ----------
        {
            uint32_t on[3] = {0,0,0}, tw[3] = {0,0,0}, fo[3] = {0,0,0};
            #pragma unroll
            for (int d = 0; d < 9; ++d)
                #pragma unroll
                for (int b = 0; b < 3; ++b) {
                    uint32_t c = on[b] & bd[d][b];
                    on[b] ^= bd[d][b];
                    fo[b] |= tw[b] & c;
                    tw[b] ^= c;
                }
            uint32_t ex1[3];
            #pragma unroll
            for (int b = 0; b < 3; ++b) ex1[b] = on[b] & ~tw[b] & ~fo[b];
            #pragma unroll
            for (int d = 0; d < 9; ++d)
                #pragma unroll
                for (int b = 0; b < 3; ++b) {
                    uint32_t s = bd[d][b] & ex1[b];
                    #pragma unroll
                    for (int k = 0; k < 3; ++k) {
                        uint32_t bm = 0x1C0E07u << (3 * k);
                        uint32_t sm = s & bm;
                        uint32_t multi = sm & (sm - 1u);
                        // 0 solved: keep all; 1 solved: keep only it; >=2: clear whole box
                        uint32_t keep = (sm == 0u) ? 0xFFFFFFFFu : (~bm | (multi ? 0u : sm));
                        bd[d][b] &= keep;
                    }
                }
        }

        // ---------- pointing 'h': box candidates confined to one row ----------
        #pragma unroll
        for (int d = 0; d < 9; ++d)
            #pragma unroll
            for (int b = 0; b < 3; ++b) {
                uint32_t w = bd[d][b];
                uint32_t t = (w | (w >> 1) | (w >> 2)) & 0x01249249u;   // presence(r,k) at bit 9r+3k
                uint32_t sum = (t & 0x1FFu) + ((t >> 9) & 0x1FFu) + ((t >> 18) & 0x1FFu);
                uint32_t single = sum & ~(sum >> 1) & 0x49u;            // nrows==1 at bit 3k
                uint32_t point = t & (single * 0x40201u);
                uint32_t clearm = 0;
                #pragma unroll
                for (int r = 0; r < 3; ++r) {
                    uint32_t pr = (point >> (9 * r)) & 0x1FFu;
                    uint32_t multi = pr & (pr - 1u);
                    uint32_t segkeep = multi ? 0u : pr * 7u;
                    uint32_t rc = pr ? ((0x1FFu & ~segkeep) << (9 * r)) : 0u;
                    clearm |= rc;
                }
                bd[d][b] = w & ~clearm;
            }

        // ---------- pointing 'v': box candidates confined to one column ----------
        #pragma unroll
        for (int d = 0; d < 9; ++d) {
            uint32_t pnt[3];
            #pragma unroll
            for (int b = 0; b < 3; ++b) {
                uint32_t w = bd[d][b];
                uint32_t q = (w | (w >> 9) | (w >> 18)) & 0x1FFu;
                uint32_t u = (q & 0x49u) + ((q >> 1) & 0x49u) + ((q >> 2) & 0x49u);
                uint32_t single = u & ~(u >> 1) & 0x49u;
                pnt[b] = q & (single * 7u);
            }
            bd[d][0] &= ~((pnt[1] | pnt[2]) * 0x40201u);
            bd[d][1] &= ~((pnt[0] | pnt[2]) * 0x40201u);
            bd[d][2] &= ~((pnt[0] | pnt[1]) * 0x40201u);
        }

        // ---------- unique 'h' (hidden single in row) ----------
        {
            uint32_t hid[9][3];
            uint32_t has[3] = {0,0,0};
            #pragma unroll
            for (int d = 0; d < 9; ++d)
                #pragma unroll
                for (int b = 0; b < 3; ++b) {
                    uint32_t w = bd[d][b], h = 0;
                    #pragma unroll
                    for (int r = 0; r < 3; ++r) {
                        uint32_t x = w & (0x1FFu << (9 * r));
                        h |= (x & (x - 1u)) ? 0u : x;
                    }
                    hid[d][b] = h;
                    has[b] |= h;
                }
            #pragma unroll
            for (int d = 0; d < 9; ++d)
                #pragma unroll
                for (int b = 0; b < 3; ++b)
                    bd[d][b] = (bd[d][b] & ~has[b]) | hid[d][b];
        }

        // ---------- unique 'v' (hidden single in column) ----------
        {
            uint32_t hid[9][3];
            uint32_t has[3] = {0,0,0};
            #pragma unroll
            for (int d = 0; d < 9; ++d) {
                uint32_t h0 = 0, h1 = 0, h2 = 0;
                #pragma unroll
                for (int c = 0; c < 9; ++c) {
                    uint32_t cm = 0x40201u << c;
                    uint32_t a0 = bd[d][0] & cm;
                    uint32_t a1 = bd[d][1] & cm;
                    uint32_t a2 = bd[d][2] & cm;
                    uint32_t cnt = (uint32_t)(__popc(a0) + __popc(a1) + __popc(a2));
                    uint32_t mm = (cnt == 1u) ? 0xFFFFFFFFu : 0u;
                    h0 |= a0 & mm; h1 |= a1 & mm; h2 |= a2 & mm;
                }
                hid[d][0] = h0; hid[d][1] = h1; hid[d][2] = h2;
                has[0] |= h0; has[1] |= h1; has[2] |= h2;
            }
            #pragma unroll
            for (int d = 0; d < 9; ++d)
                #pragma unroll
                for (int b = 0; b < 3; ++b)
                    bd[d][b] = (bd[d][b] & ~has[b]) | hid[d][b];
        }

        // ---------- unique 'box' (hidden single in box) ----------
        {
            uint32_t hid[9][3];
            uint32_t has[3] = {0,0,0};
            #pragma unroll
            for (int d = 0; d < 9; ++d)
                #pragma unroll
                for (int b = 0; b < 3; ++b) {
                    uint32_t w = bd[d][b], h = 0;
                    #pragma unroll
                    for (int k = 0; k < 3; ++k) {
                        uint32_t x = w & (0x1C0E07u << (3 * k));
                        h |= (x & (x - 1u)) ? 0u : x;
                    }
                    hid[d][b] = h;
                    has[b] |= h;
                }
            #pragma unroll
            for (int d = 0; d < 9; ++d)
                #pragma unroll
                for (int b = 0; b < 3; ++b)
                    bd[d][b] = (bd[d][b] & ~has[b]) | hid[d][b];
        }

        // ---------- doubles 'v' twice (naked pairs on columns) ----------
        for (int rep = 0; rep < 2; ++rep) {
            uint32_t on[3] = {0,0,0}, tw[3] = {0,0,0}, fo[3] = {0,0,0};
            #pragma unroll
            for (int d = 0; d < 9; ++d)
                #pragma unroll
                for (int b = 0; b < 3; ++b) {
                    uint32_t c = on[b] & bd[d][b];
                    on[b] ^= bd[d][b];
                    fo[b] |= tw[b] & c;
                    tw[b] ^= c;
                }
            uint32_t ex2[3], Q[9][3], K[9][3];
            #pragma unroll
            for (int b = 0; b < 3; ++b) ex2[b] = tw[b] & ~on[b] & ~fo[b];
            #pragma unroll
            for (int d = 0; d < 9; ++d)
                #pragma unroll
                for (int b = 0; b < 3; ++b) { Q[d][b] = bd[d][b] & ex2[b]; K[d][b] = 0u; }
            #pragma unroll
            for (int d1 = 0; d1 < 9; ++d1)
                #pragma unroll
                for (int d2 = d1 + 1; d2 < 9; ++d2) {
                    uint32_t P0 = Q[d1][0] & Q[d2][0];   // cells with pattern exactly {d1,d2}
                    uint32_t P1 = Q[d1][1] & Q[d2][1];
                    uint32_t P2 = Q[d1][2] & Q[d2][2];
                    uint32_t f0 = (P0 | (P0 >> 9) | (P0 >> 18)) & 0x1FFu;
                    uint32_t f1 = (P1 | (P1 >> 9) | (P1 >> 18)) & 0x1FFu;
                    uint32_t f2 = (P2 | (P2 >> 9) | (P2 >> 18)) & 0x1FFu;
                    uint32_t g0 = ((P0 & (P0 >> 9)) | ((P0 | (P0 >> 9)) & (P0 >> 18))) & 0x1FFu;
                    uint32_t g1 = ((P1 & (P1 >> 9)) | ((P1 | (P1 >> 9)) & (P1 >> 18))) & 0x1FFu;
                    uint32_t g2 = ((P2 & (P2 >> 9)) | ((P2 | (P2 >> 9)) & (P2 >> 18))) & 0x1FFu;
                    // columns with >=2 such cells: >=2 in one band, or presence in >=2 bands
                    uint32_t dup = g0 | g1 | g2 | (f0 & f1) | (f0 & f2) | (f1 & f2);
                    uint32_t em = dup * 0x40201u;
                    uint32_t s0 = P0 & em, s1 = P1 & em, s2 = P2 & em;
                    K[d1][0] |= s0; K[d1][1] |= s1; K[d1][2] |= s2;
                    K[d2][0] |= s0; K[d2][1] |= s1; K[d2][2] |= s2;
                }
            #pragma unroll
            for (int d = 0; d < 9; ++d) {
                uint32_t fold = K[d][0] | K[d][1] | K[d][2];
                uint32_t cols = (fold | (fold >> 9) | (fold >> 18)) & 0x1FFu;
                uint32_t em = cols * 0x40201u;
                #pragma unroll
                for (int b = 0; b < 3; ++b)
                    bd[d][b] = (bd[d][b] & ~em) | K[d][b];
            }
        }

        // ---------- doubles 'box' (naked pairs in boxes) ----------
        {
            uint32_t on[3] = {0,0,0}, tw[3] = {0,0,0}, fo[3] = {0,0,0};
            #pragma unroll
            for (int d = 0; d < 9; ++d)
                #pragma unroll
                for (int b = 0; b < 3; ++b) {
                    uint32_t c = on[b] & bd[d][b];
                    on[b] ^= bd[d][b];
                    fo[b] |= tw[b] & c;
                    tw[b] ^= c;
                }
            uint32_t ex2[3], Q[9][3], K[9][3];
            #pragma unroll
            for (int b = 0; b < 3; ++b) ex2[b] = tw[b] & ~on[b] & ~fo[b];
            #pragma unroll
            for (int d = 0; d < 9; ++d)
                #pragma unroll
                for (int b = 0; b < 3; ++b) { Q[d][b] = bd[d][b] & ex2[b]; K[d][b] = 0u; }
            #pragma unroll
            for (int d1 = 0; d1 < 9; ++d1)
                #pragma unroll
                for (int d2 = d1 + 1; d2 < 9; ++d2)
                    #pragma unroll
                    for (int b = 0; b < 3; ++b) {
                        uint32_t P = Q[d1][b] & Q[d2][b];
                        #pragma unroll
                        for (int k = 0; k < 3; ++k) {
                            uint32_t m = P & (0x1C0E07u << (3 * k));
                            uint32_t s = (m & (m - 1u)) ? m : 0u;   // >=2 cells in the box
                            K[d1][b] |= s; K[d2][b] |= s;
                        }
                    }
            #pragma unroll
            for (int d = 0; d < 9; ++d)
                #pragma unroll
                for (int b = 0; b < 3; ++b)
                    #pragma unroll
                    for (int k = 0; k < 3; ++k) {
                        uint32_t bm = 0x1C0E07u << (3 * k);
                        uint32_t t = K[d][b] & bm;
                        uint32_t mask = t ? (~bm | t) : 0xFFFFFFFFu;
                        bd[d][b] &= mask;
                    }
        }
    } // passes

    // ---------------- solved flag (in-register, direct store) ----------------
    {
        uint32_t on[3] = {0,0,0}, tw[3] = {0,0,0}, fo[3] = {0,0,0};
        #pragma unroll
        for (int d = 0; d < 9; ++d)
            #pragma unroll
            for (int b = 0; b < 3; ++b) {
                uint32_t c = on[b] & bd[d][b];
                on[b] ^= bd[d][b];
                fo[b] |= tw[b] & c;
                tw[b] ^= c;
            }
        bool ok = ((on[0] & ~tw[0] & ~fo[0]) == FULL27) &&
                  ((on[1] & ~tw[1] & ~fo[1]) == FULL27) &&
                  ((on[2] & ~tw[2] & ~fo[2]) == FULL27);
        solved[blockBase + lane] = ok ? 1.0f : 0.0f;
    }

    // ---------------- WRITEBACK: zero pool, OR result bits in ----------------
    __syncthreads();                                       // pack-phase pool reads done
    for (int j = lane; j < 1460; j += 64) pool[j] = 0u;
    __syncthreads();
    {
        const int base = lane * 729;
        #pragma unroll
        for (int q = 0; q < 27; ++q) {
            int bit = base + q * 27;
            int di = bit >> 5;
            int sh = bit & 31;
            uint64_t both = (uint64_t)bd[q / 3][q % 3] << sh;
            atomicOr(&pool[di], (uint32_t)both);
            atomicOr(&pool[di + 1], (uint32_t)(both >> 32));
        }
    }
    __syncthreads();

    // ---------------- EXPAND: broadcast LDS reads -> coalesced float stores ----------------
    #pragma unroll 9
    for (int i = 0; i < 729; ++i) {
        uint32_t dw = pool[2 * i + (lane >> 5)];
        dst[i * 64 + lane] = (float)((dw >> (lane & 31)) & 1u);
    }
}

extern "C" void kernel_launch(void* const* d_in, const int* in_sizes, int n_in,
                              void* d_out, int out_size, void* d_ws, size_t ws_size,
                              hipStream_t stream) {
    const uint32_t* in = (const uint32_t*)d_in[0];   // float32 bits; nonzero <=> 1.0f
    float* out = (float*)d_out;
    float* solved = out + (size_t)NB * 729;
    sudoku_fused_kernel<<<NB / 64, 64, 0, stream>>>(in, out, solved);
}

// Round 4
// 256.271 us; speedup vs baseline: 2.0399x; 2.0399x over previous
//
#include <hip/hip_runtime.h>
#include <stdint.h>

#define NB 32768
#define NPASS 4
#define FULL27 0x07FFFFFFu
#define NWORDS (NB * 27)   // 884736 packed words

// layout: per puzzle, 27 words; word (d*3+b) = digit d, band b (rows 3b..3b+2),
// bit (r*9+c) with r = local row 0..2, c = column 0..8.
// BOX k mask within band: 0x1C0E07 << 3k ; COL c: 0x40201 << c ; ROW r: 0x1FF << 9r
// Packed word w == bits of input floats [27w .. 27w+26] (flat order matches).

// ---------------- PACK: wave ballot -> 64 words per wave ----------------
// Wave handles 64 consecutive words = 1728 consecutive floats, read as 27
// perfectly-coalesced 64-lane rounds. Ballot masks land in a 54-dword LDS
// strip per wave; each lane then extracts its 27-bit word.
__global__ __launch_bounds__(256)
void pack_kernel(const uint32_t* __restrict__ in, uint32_t* __restrict__ packed) {
    __shared__ uint32_t pool[4][56];
    const int lane = threadIdx.x & 63;
    const int wv = threadIdx.x >> 6;
    const size_t wordBase = (size_t)blockIdx.x * 256 + (size_t)wv * 64;
    const uint32_t* src = in + wordBase * 27;
    #pragma unroll
    for (int i = 0; i < 27; ++i) {
        uint32_t v = src[(size_t)i * 64 + lane];
        unsigned long long m = __ballot(v != 0u);
        if (lane == 0) {
            pool[wv][2 * i]     = (uint32_t)m;
            pool[wv][2 * i + 1] = (uint32_t)(m >> 32);
        }
    }
    __syncthreads();
    const int bit = lane * 27;          // bit offset in this wave's 1728-bit strip
    const int di = bit >> 5;            // max 53; di+1 <= 54 < 56
    uint64_t both = (uint64_t)pool[wv][di] | ((uint64_t)pool[wv][di + 1] << 32);
    packed[wordBase + lane] = (uint32_t)(both >> (bit & 31)) & FULL27;
}

// ---------------- SOLVE: validated round-2 logic, 1 thread = 1 puzzle ----------------
// block=256: 4 waves share one CU's L1I. unroll-1 on pass/rep loops keeps the
// code body ~4x smaller (I-cache: ~200KB unrolled >> 32KB L1I at 1 wave/SIMD).
__global__ __launch_bounds__(256, 1)
void solve_kernel(const uint32_t* __restrict__ pin, uint32_t* __restrict__ pout,
                  float* __restrict__ solved) {
    int p = blockIdx.x * blockDim.x + threadIdx.x;
    if (p >= NB) return;
    uint32_t bd[9][3];
    {
        const uint32_t* src = pin + (size_t)p * 27;
        #pragma unroll
        for (int i = 0; i < 27; ++i) bd[i / 3][i % 3] = src[i];
    }

    #pragma unroll 1
    for (int pass = 0; pass < NPASS; ++pass) {
        // ---------- filter 'box': solved cell eliminates digit from rest of box ----------
        {
            uint32_t on[3] = {0,0,0}, tw[3] = {0,0,0}, fo[3] = {0,0,0};
            #pragma unroll
            for (int d = 0; d < 9; ++d)
                #pragma unroll
                for (int b = 0; b < 3; ++b) {
                    uint32_t c = on[b] & bd[d][b];
                    on[b] ^= bd[d][b];
                    fo[b] |= tw[b] & c;
                    tw[b] ^= c;
                }
            uint32_t ex1[3];
            #pragma unroll
            for (int b = 0; b < 3; ++b) ex1[b] = on[b] & ~tw[b] & ~fo[b];
            #pragma unroll
            for (int d = 0; d < 9; ++d)
                #pragma unroll
                for (int b = 0; b < 3; ++b) {
                    uint32_t s = bd[d][b] & ex1[b];
                    #pragma unroll
                    for (int k = 0; k < 3; ++k) {
                        uint32_t bm = 0x1C0E07u << (3 * k);
                        uint32_t sm = s & bm;
                        uint32_t multi = sm & (sm - 1u);
                        // 0 solved: keep all; 1 solved: keep only it; >=2: clear whole box
                        uint32_t keep = (sm == 0u) ? 0xFFFFFFFFu : (~bm | (multi ? 0u : sm));
                        bd[d][b] &= keep;
                    }
                }
        }

        // ---------- pointing 'h': box candidates confined to one row ----------
        #pragma unroll
        for (int d = 0; d < 9; ++d)
            #pragma unroll
            for (int b = 0; b < 3; ++b) {
                uint32_t w = bd[d][b];
                uint32_t t = (w | (w >> 1) | (w >> 2)) & 0x01249249u;   // presence(r,k) at bit 9r+3k
                uint32_t sum = (t & 0x1FFu) + ((t >> 9) & 0x1FFu) + ((t >> 18) & 0x1FFu);
                uint32_t single = sum & ~(sum >> 1) & 0x49u;            // nrows==1 at bit 3k
                uint32_t point = t & (single * 0x40201u);
                uint32_t clearm = 0;
                #pragma unroll
                for (int r = 0; r < 3; ++r) {
                    uint32_t pr = (point >> (9 * r)) & 0x1FFu;
                    uint32_t multi = pr & (pr - 1u);
                    uint32_t segkeep = multi ? 0u : pr * 7u;
                    uint32_t rc = pr ? ((0x1FFu & ~segkeep) << (9 * r)) : 0u;
                    clearm |= rc;
                }
                bd[d][b] = w & ~clearm;
            }

        // ---------- pointing 'v': box candidates confined to one column ----------
        #pragma unroll
        for (int d = 0; d < 9; ++d) {
            uint32_t pnt[3];
            #pragma unroll
            for (int b = 0; b < 3; ++b) {
                uint32_t w = bd[d][b];
                uint32_t q = (w | (w >> 9) | (w >> 18)) & 0x1FFu;
                uint32_t u = (q & 0x49u) + ((q >> 1) & 0x49u) + ((q >> 2) & 0x49u);
                uint32_t single = u & ~(u >> 1) & 0x49u;
                pnt[b] = q & (single * 7u);
            }
            bd[d][0] &= ~((pnt[1] | pnt[2]) * 0x40201u);
            bd[d][1] &= ~((pnt[0] | pnt[2]) * 0x40201u);
            bd[d][2] &= ~((pnt[0] | pnt[1]) * 0x40201u);
        }

        // ---------- unique 'h' (hidden single in row) ----------
        {
            uint32_t hid[9][3];
            uint32_t has[3] = {0,0,0};
            #pragma unroll
            for (int d = 0; d < 9; ++d)
                #pragma unroll
                for (int b = 0; b < 3; ++b) {
                    uint32_t w = bd[d][b], h = 0;
                    #pragma unroll
                    for (int r = 0; r < 3; ++r) {
                        uint32_t x = w & (0x1FFu << (9 * r));
                        h |= (x & (x - 1u)) ? 0u : x;
                    }
                    hid[d][b] = h;
                    has[b] |= h;
                }
            #pragma unroll
            for (int d = 0; d < 9; ++d)
                #pragma unroll
                for (int b = 0; b < 3; ++b)
                    bd[d][b] = (bd[d][b] & ~has[b]) | hid[d][b];
        }

        // ---------- unique 'v' (hidden single in column) ----------
        {
            uint32_t hid[9][3];
            uint32_t has[3] = {0,0,0};
            #pragma unroll
            for (int d = 0; d < 9; ++d) {
                uint32_t h0 = 0, h1 = 0, h2 = 0;
                #pragma unroll
                for (int c = 0; c < 9; ++c) {
                    uint32_t cm = 0x40201u << c;
                    uint32_t a0 = bd[d][0] & cm;
                    uint32_t a1 = bd[d][1] & cm;
                    uint32_t a2 = bd[d][2] & cm;
                    uint32_t cnt = (uint32_t)(__popc(a0) + __popc(a1) + __popc(a2));
                    uint32_t mm = (cnt == 1u) ? 0xFFFFFFFFu : 0u;
                    h0 |= a0 & mm; h1 |= a1 & mm; h2 |= a2 & mm;
                }
                hid[d][0] = h0; hid[d][1] = h1; hid[d][2] = h2;
                has[0] |= h0; has[1] |= h1; has[2] |= h2;
            }
            #pragma unroll
            for (int d = 0; d < 9; ++d)
                #pragma unroll
                for (int b = 0; b < 3; ++b)
                    bd[d][b] = (bd[d][b] & ~has[b]) | hid[d][b];
        }

        // ---------- unique 'box' (hidden single in box) ----------
        {
            uint32_t hid[9][3];
            uint32_t has[3] = {0,0,0};
            #pragma unroll
            for (int d = 0; d < 9; ++d)
                #pragma unroll
                for (int b = 0; b < 3; ++b) {
                    uint32_t w = bd[d][b], h = 0;
                    #pragma unroll
                    for (int k = 0; k < 3; ++k) {
                        uint32_t x = w & (0x1C0E07u << (3 * k));
                        h |= (x & (x - 1u)) ? 0u : x;
                    }
                    hid[d][b] = h;
                    has[b] |= h;
                }
            #pragma unroll
            for (int d = 0; d < 9; ++d)
                #pragma unroll
                for (int b = 0; b < 3; ++b)
                    bd[d][b] = (bd[d][b] & ~has[b]) | hid[d][b];
        }

        // ---------- doubles 'v' twice (naked pairs on columns) ----------
        #pragma unroll 1
        for (int rep = 0; rep < 2; ++rep) {
            uint32_t on[3] = {0,0,0}, tw[3] = {0,0,0}, fo[3] = {0,0,0};
            #pragma unroll
            for (int d = 0; d < 9; ++d)
                #pragma unroll
                for (int b = 0; b < 3; ++b) {
                    uint32_t c = on[b] & bd[d][b];
                    on[b] ^= bd[d][b];
                    fo[b] |= tw[b] & c;
                    tw[b] ^= c;
                }
            uint32_t ex2[3], Q[9][3], K[9][3];
            #pragma unroll
            for (int b = 0; b < 3; ++b) ex2[b] = tw[b] & ~on[b] & ~fo[b];
            #pragma unroll
            for (int d = 0; d < 9; ++d)
                #pragma unroll
                for (int b = 0; b < 3; ++b) { Q[d][b] = bd[d][b] & ex2[b]; K[d][b] = 0u; }
            #pragma unroll
            for (int d1 = 0; d1 < 9; ++d1)
                #pragma unroll
                for (int d2 = d1 + 1; d2 < 9; ++d2) {
                    uint32_t P0 = Q[d1][0] & Q[d2][0];   // cells with pattern exactly {d1,d2}
                    uint32_t P1 = Q[d1][1] & Q[d2][1];
                    uint32_t P2 = Q[d1][2] & Q[d2][2];
                    uint32_t f0 = (P0 | (P0 >> 9) | (P0 >> 18)) & 0x1FFu;
                    uint32_t f1 = (P1 | (P1 >> 9) | (P1 >> 18)) & 0x1FFu;
                    uint32_t f2 = (P2 | (P2 >> 9) | (P2 >> 18)) & 0x1FFu;
                    uint32_t g0 = ((P0 & (P0 >> 9)) | ((P0 | (P0 >> 9)) & (P0 >> 18))) & 0x1FFu;
                    uint32_t g1 = ((P1 & (P1 >> 9)) | ((P1 | (P1 >> 9)) & (P1 >> 18))) & 0x1FFu;
                    uint32_t g2 = ((P2 & (P2 >> 9)) | ((P2 | (P2 >> 9)) & (P2 >> 18))) & 0x1FFu;
                    // columns with >=2 such cells: >=2 in one band, or presence in >=2 bands
                    uint32_t dup = g0 | g1 | g2 | (f0 & f1) | (f0 & f2) | (f1 & f2);
                    uint32_t em = dup * 0x40201u;
                    uint32_t s0 = P0 & em, s1 = P1 & em, s2 = P2 & em;
                    K[d1][0] |= s0; K[d1][1] |= s1; K[d1][2] |= s2;
                    K[d2][0] |= s0; K[d2][1] |= s1; K[d2][2] |= s2;
                }
            #pragma unroll
            for (int d = 0; d < 9; ++d) {
                uint32_t fold = K[d][0] | K[d][1] | K[d][2];
                uint32_t cols = (fold | (fold >> 9) | (fold >> 18)) & 0x1FFu;
                uint32_t em = cols * 0x40201u;
                #pragma unroll
                for (int b = 0; b < 3; ++b)
                    bd[d][b] = (bd[d][b] & ~em) | K[d][b];
            }
        }

        // ---------- doubles 'box' (naked pairs in boxes) ----------
        {
            uint32_t on[3] = {0,0,0}, tw[3] = {0,0,0}, fo[3] = {0,0,0};
            #pragma unroll
            for (int d = 0; d < 9; ++d)
                #pragma unroll
                for (int b = 0; b < 3; ++b) {
                    uint32_t c = on[b] & bd[d][b];
                    on[b] ^= bd[d][b];
                    fo[b] |= tw[b] & c;
                    tw[b] ^= c;
                }
            uint32_t ex2[3], Q[9][3], K[9][3];
            #pragma unroll
            for (int b = 0; b < 3; ++b) ex2[b] = tw[b] & ~on[b] & ~fo[b];
            #pragma unroll
            for (int d = 0; d < 9; ++d)
                #pragma unroll
                for (int b = 0; b < 3; ++b) { Q[d][b] = bd[d][b] & ex2[b]; K[d][b] = 0u; }
            #pragma unroll
            for (int d1 = 0; d1 < 9; ++d1)
                #pragma unroll
                for (int d2 = d1 + 1; d2 < 9; ++d2)
                    #pragma unroll
                    for (int b = 0; b < 3; ++b) {
                        uint32_t P = Q[d1][b] & Q[d2][b];
                        #pragma unroll
                        for (int k = 0; k < 3; ++k) {
                            uint32_t m = P & (0x1C0E07u << (3 * k));
                            uint32_t s = (m & (m - 1u)) ? m : 0u;   // >=2 cells in the box
                            K[d1][b] |= s; K[d2][b] |= s;
                        }
                    }
            #pragma unroll
            for (int d = 0; d < 9; ++d)
                #pragma unroll
                for (int b = 0; b < 3; ++b)
                    #pragma unroll
                    for (int k = 0; k < 3; ++k) {
                        uint32_t bm = 0x1C0E07u << (3 * k);
                        uint32_t t = K[d][b] & bm;
                        uint32_t mask = t ? (~bm | t) : 0xFFFFFFFFu;
                        bd[d][b] &= mask;
                    }
        }
    } // passes

    // store packed result
    {
        uint32_t* dst = pout + (size_t)p * 27;
        #pragma unroll
        for (int i = 0; i < 27; ++i) dst[i] = bd[i / 3][i % 3];
    }
    // solved flag: every cell has exactly one candidate
    {
        uint32_t on[3] = {0,0,0}, tw[3] = {0,0,0}, fo[3] = {0,0,0};
        #pragma unroll
        for (int d = 0; d < 9; ++d)
            #pragma unroll
            for (int b = 0; b < 3; ++b) {
                uint32_t c = on[b] & bd[d][b];
                on[b] ^= bd[d][b];
                fo[b] |= tw[b] & c;
                tw[b] ^= c;
            }
        bool ok = ((on[0] & ~tw[0] & ~fo[0]) == FULL27) &&
                  ((on[1] & ~tw[1] & ~fo[1]) == FULL27) &&
                  ((on[2] & ~tw[2] & ~fo[2]) == FULL27);
        solved[p] = ok ? 1.0f : 0.0f;
    }
}

// ---------------- EXPAND: 4 elements/thread, float4 stores ----------------
__global__ __launch_bounds__(256)
void expand_kernel(const uint32_t* __restrict__ packed, float4* __restrict__ out4) {
    int tid = blockIdx.x * blockDim.x + threadIdx.x;
    int base = tid * 4;                         // flat element index, < 23.9M
    int w0 = (int)((unsigned)base / 27u);
    int pos0 = base - w0 * 27;
    uint32_t a = packed[w0];
    int w1 = w0 + 1; if (w1 > NWORDS - 1) w1 = NWORDS - 1;
    uint32_t b = packed[w1];
    float r[4];
    #pragma unroll
    for (int k = 0; k < 4; ++k) {
        int pp = pos0 + k;
        uint32_t word = (pp < 27) ? a : b;
        int sh = (pp < 27) ? pp : pp - 27;
        r[k] = (float)((word >> sh) & 1u);
    }
    out4[tid] = make_float4(r[0], r[1], r[2], r[3]);
}

extern "C" void kernel_launch(void* const* d_in, const int* in_sizes, int n_in,
                              void* d_out, int out_size, void* d_ws, size_t ws_size,
                              hipStream_t stream) {
    const uint32_t* in = (const uint32_t*)d_in[0];   // float32 bits; nonzero <=> 1.0f
    float* out = (float*)d_out;
    float* solved = out + (size_t)NB * 729;
    uint32_t* packed = (uint32_t*)d_ws;              // NWORDS words = 3.54 MB

    pack_kernel<<<NWORDS / 256, 256, 0, stream>>>(in, packed);       // 3456 blocks
    // solve reads then overwrites its own 27 words: safe in-place
    solve_kernel<<<NB / 256, 256, 0, stream>>>(packed, packed, solved); // 128 blocks
    expand_kernel<<<(NB * 729 / 4) / 256, 256, 0, stream>>>(packed, (float4*)out); // 23328 blocks
}

// Round 5
// 235.425 us; speedup vs baseline: 2.2205x; 1.0885x over previous
//
#include <hip/hip_runtime.h>
#include <stdint.h>

#define NB 32768
#define NPASS 4
#define FULL27 0x07FFFFFFu
#define NWORDS (NB * 27)   // 884736 packed words

// layout: per puzzle, 27 words; word (d*3+b) = digit d, band b (rows 3b..3b+2),
// bit (r*9+c) with r = local row 0..2, c = column 0..8.
// BOX k mask within band: 0x1C0E07 << 3k ; COL c: 0x40201 << c ; ROW r: 0x1FF << 9r
// Packed word w == bits of input floats [27w .. 27w+26] (flat order matches).

// ---------------- PACK: wave ballot -> 64 words per wave (validated r4) ----------------
__global__ __launch_bounds__(256)
void pack_kernel(const uint32_t* __restrict__ in, uint32_t* __restrict__ packed) {
    __shared__ uint32_t pool[4][56];
    const int lane = threadIdx.x & 63;
    const int wv = threadIdx.x >> 6;
    const size_t wordBase = (size_t)blockIdx.x * 256 + (size_t)wv * 64;
    const uint32_t* src = in + wordBase * 27;
    #pragma unroll
    for (int i = 0; i < 27; ++i) {
        uint32_t v = src[(size_t)i * 64 + lane];
        unsigned long long m = __ballot(v != 0u);
        if (lane == 0) {
            pool[wv][2 * i]     = (uint32_t)m;
            pool[wv][2 * i + 1] = (uint32_t)(m >> 32);
        }
    }
    __syncthreads();
    const int bit = lane * 27;
    const int di = bit >> 5;
    uint64_t both = (uint64_t)pool[wv][di] | ((uint64_t)pool[wv][di + 1] << 32);
    packed[wordBase + lane] = (uint32_t)(both >> (bit & 31)) & FULL27;
}

__device__ __forceinline__ uint32_t colfold(uint32_t w) {
    return (w | (w >> 9) | (w >> 18)) & 0x1FFu;
}
__device__ __forceinline__ uint32_t colmaj2(uint32_t w) {   // columns with >=2 bits in band
    return ((w & (w >> 9)) | ((w | (w >> 9)) & (w >> 18))) & 0x1FFu;
}

// ---------------- SOLVE: 3 threads per puzzle (one band each) ----------------
// Block = 192 threads: wave b = band b for 64 puzzles (lane = puzzle-in-block).
// Cross-band ops (pointing-v, unique-v, doubles-v) exchange 9..36 small masks
// via ping-pong LDS (A,B alternate -> one __syncthreads per exchange is safe).
__global__ __launch_bounds__(192, 1)
void solve_kernel(const uint32_t* __restrict__ pin, uint32_t* __restrict__ pout,
                  float* __restrict__ solved) {
    __shared__ uint32_t exA[3][36][64];   // pair exchange (and solved flag)
    __shared__ uint32_t exB[3][9][64];    // per-digit exchange
    const int lane = threadIdx.x & 63;    // puzzle within block
    const int band = threadIdx.x >> 6;    // 0..2 == wave id
    const int bo1 = band == 2 ? 0 : band + 1;
    const int bo2 = band == 0 ? 2 : band - 1;
    const int p = blockIdx.x * 64 + lane;

    uint32_t bd[9];
    {
        const uint32_t* src = pin + (size_t)p * 27 + band;
        #pragma unroll
        for (int d = 0; d < 9; ++d) bd[d] = src[d * 3];
    }

    #pragma unroll 1
    for (int pass = 0; pass < NPASS; ++pass) {
        // ---------- filter 'box' (band-local) ----------
        {
            uint32_t on = 0, tw = 0, fo = 0;
            #pragma unroll
            for (int d = 0; d < 9; ++d) {
                uint32_t c = on & bd[d];
                on ^= bd[d]; fo |= tw & c; tw ^= c;
            }
            uint32_t ex1 = on & ~tw & ~fo;
            #pragma unroll
            for (int d = 0; d < 9; ++d) {
                uint32_t s = bd[d] & ex1;
                #pragma unroll
                for (int k = 0; k < 3; ++k) {
                    uint32_t bm = 0x1C0E07u << (3 * k);
                    uint32_t sm = s & bm;
                    uint32_t multi = sm & (sm - 1u);
                    uint32_t keep = (sm == 0u) ? 0xFFFFFFFFu : (~bm | (multi ? 0u : sm));
                    bd[d] &= keep;
                }
            }
        }

        // ---------- pointing 'h' (band-local) ----------
        #pragma unroll
        for (int d = 0; d < 9; ++d) {
            uint32_t w = bd[d];
            uint32_t t = (w | (w >> 1) | (w >> 2)) & 0x01249249u;
            uint32_t sum = (t & 0x1FFu) + ((t >> 9) & 0x1FFu) + ((t >> 18) & 0x1FFu);
            uint32_t single = sum & ~(sum >> 1) & 0x49u;
            uint32_t point = t & (single * 0x40201u);
            uint32_t clearm = 0;
            #pragma unroll
            for (int r = 0; r < 3; ++r) {
                uint32_t pr = (point >> (9 * r)) & 0x1FFu;
                uint32_t multi = pr & (pr - 1u);
                uint32_t segkeep = multi ? 0u : pr * 7u;
                uint32_t rc = pr ? ((0x1FFu & ~segkeep) << (9 * r)) : 0u;
                clearm |= rc;
            }
            bd[d] = w & ~clearm;
        }

        // ---------- pointing 'v' (cross-band, exchange A) ----------
        #pragma unroll
        for (int d = 0; d < 9; ++d) {
            uint32_t w = bd[d];
            uint32_t q = colfold(w);
            uint32_t u = (q & 0x49u) + ((q >> 1) & 0x49u) + ((q >> 2) & 0x49u);
            uint32_t single = u & ~(u >> 1) & 0x49u;
            exA[band][d][lane] = q & (single * 7u);      // this band's pointing cols
        }
        __syncthreads();
        #pragma unroll
        for (int d = 0; d < 9; ++d) {
            uint32_t o = exA[bo1][d][lane] | exA[bo2][d][lane];
            bd[d] &= ~(o * 0x40201u);
        }

        // ---------- unique 'h' (band-local) ----------
        {
            uint32_t hid[9], has = 0;
            #pragma unroll
            for (int d = 0; d < 9; ++d) {
                uint32_t w = bd[d], h = 0;
                #pragma unroll
                for (int r = 0; r < 3; ++r) {
                    uint32_t x = w & (0x1FFu << (9 * r));
                    h |= (x & (x - 1u)) ? 0u : x;
                }
                hid[d] = h; has |= h;
            }
            #pragma unroll
            for (int d = 0; d < 9; ++d) bd[d] = (bd[d] & ~has) | hid[d];
        }

        // ---------- unique 'v' (cross-band, exchange B) ----------
        {
            #pragma unroll
            for (int d = 0; d < 9; ++d) {
                uint32_t w = bd[d];
                exB[band][d][lane] = colfold(w) | (colmaj2(w) << 9);
            }
            __syncthreads();
            uint32_t hid[9], has = 0;
            #pragma unroll
            for (int d = 0; d < 9; ++d) {
                uint32_t w = bd[d];
                uint32_t q0 = colfold(w), m0 = colmaj2(w);
                uint32_t ea = exB[bo1][d][lane], eb = exB[bo2][d][lane];
                uint32_t qa = ea & 0x1FFu, ma = ea >> 9;
                uint32_t qb = eb & 0x1FFu, mb = eb >> 9;
                uint32_t ge2 = m0 | ma | mb | (q0 & qa) | (q0 & qb) | (qa & qb);
                uint32_t ex1c = (q0 | qa | qb) & ~ge2;   // column total count == 1
                hid[d] = w & ((ex1c & q0) * 0x40201u);
                has |= hid[d];
            }
            #pragma unroll
            for (int d = 0; d < 9; ++d) bd[d] = (bd[d] & ~has) | hid[d];
        }

        // ---------- unique 'box' (band-local) ----------
        {
            uint32_t hid[9], has = 0;
            #pragma unroll
            for (int d = 0; d < 9; ++d) {
                uint32_t w = bd[d], h = 0;
                #pragma unroll
                for (int k = 0; k < 3; ++k) {
                    uint32_t x = w & (0x1C0E07u << (3 * k));
                    h |= (x & (x - 1u)) ? 0u : x;
                }
                hid[d] = h; has |= h;
            }
            #pragma unroll
            for (int d = 0; d < 9; ++d) bd[d] = (bd[d] & ~has) | hid[d];
        }

        // ---------- doubles 'v' twice (cross-band: pairs via A, K-cols via B) ----------
        #pragma unroll 1
        for (int rep = 0; rep < 2; ++rep) {
            uint32_t on = 0, tw = 0, fo = 0;
            #pragma unroll
            for (int d = 0; d < 9; ++d) {
                uint32_t c = on & bd[d];
                on ^= bd[d]; fo |= tw & c; tw ^= c;
            }
            uint32_t ex2 = tw & ~on & ~fo;
            uint32_t Q[9], K[9];
            #pragma unroll
            for (int d = 0; d < 9; ++d) { Q[d] = bd[d] & ex2; K[d] = 0u; }
            {
                int s = 0;
                #pragma unroll
                for (int d1 = 0; d1 < 9; ++d1)
                    #pragma unroll
                    for (int d2 = d1 + 1; d2 < 9; ++d2) {
                        uint32_t P = Q[d1] & Q[d2];
                        exA[band][s][lane] = colfold(P) | (colmaj2(P) << 9);
                        ++s;
                    }
            }
            __syncthreads();
            {
                int s = 0;
                #pragma unroll
                for (int d1 = 0; d1 < 9; ++d1)
                    #pragma unroll
                    for (int d2 = d1 + 1; d2 < 9; ++d2) {
                        uint32_t P = Q[d1] & Q[d2];
                        uint32_t f0 = colfold(P), g0 = colmaj2(P);
                        uint32_t ea = exA[bo1][s][lane], eb = exA[bo2][s][lane];
                        uint32_t fa = ea & 0x1FFu, ga = ea >> 9;
                        uint32_t fb = eb & 0x1FFu, gb = eb >> 9;
                        // columns with >=2 exact-pair cells across the full column
                        uint32_t dup = g0 | ga | gb | (f0 & fa) | (f0 & fb) | (fa & fb);
                        uint32_t sK = P & (dup * 0x40201u);
                        K[d1] |= sK; K[d2] |= sK;
                        ++s;
                    }
            }
            #pragma unroll
            for (int d = 0; d < 9; ++d) exB[band][d][lane] = colfold(K[d]);
            __syncthreads();
            #pragma unroll
            for (int d = 0; d < 9; ++d) {
                uint32_t cols = colfold(K[d]) | exB[bo1][d][lane] | exB[bo2][d][lane];
                uint32_t em = cols * 0x40201u;
                bd[d] = (bd[d] & ~em) | K[d];
            }
        }

        // ---------- doubles 'box' (band-local) ----------
        {
            uint32_t on = 0, tw = 0, fo = 0;
            #pragma unroll
            for (int d = 0; d < 9; ++d) {
                uint32_t c = on & bd[d];
                on ^= bd[d]; fo |= tw & c; tw ^= c;
            }
            uint32_t ex2 = tw & ~on & ~fo;
            uint32_t Q[9], K[9];
            #pragma unroll
            for (int d = 0; d < 9; ++d) { Q[d] = bd[d] & ex2; K[d] = 0u; }
            #pragma unroll
            for (int d1 = 0; d1 < 9; ++d1)
                #pragma unroll
                for (int d2 = d1 + 1; d2 < 9; ++d2) {
                    uint32_t P = Q[d1] & Q[d2];
                    #pragma unroll
                    for (int k = 0; k < 3; ++k) {
                        uint32_t m = P & (0x1C0E07u << (3 * k));
                        uint32_t s = (m & (m - 1u)) ? m : 0u;
                        K[d1] |= s; K[d2] |= s;
                    }
                }
            #pragma unroll
            for (int d = 0; d < 9; ++d)
                #pragma unroll
                for (int k = 0; k < 3; ++k) {
                    uint32_t bm = 0x1C0E07u << (3 * k);
                    uint32_t t = K[d] & bm;
                    uint32_t mask = t ? (~bm | t) : 0xFFFFFFFFu;
                    bd[d] &= mask;
                }
        }
    } // passes

    // store packed result
    {
        uint32_t* dst = pout + (size_t)p * 27 + band;
        #pragma unroll
        for (int d = 0; d < 9; ++d) dst[d * 3] = bd[d];
    }
    // solved flag: all cells count==1 in every band
    {
        uint32_t on = 0, tw = 0, fo = 0;
        #pragma unroll
        for (int d = 0; d < 9; ++d) {
            uint32_t c = on & bd[d];
            on ^= bd[d]; fo |= tw & c; tw ^= c;
        }
        exA[band][0][lane] = ((on & ~tw & ~fo) == FULL27) ? 1u : 0u;
        __syncthreads();
        if (band == 0) {
            uint32_t all = exA[0][0][lane] & exA[1][0][lane] & exA[2][0][lane];
            solved[p] = all ? 1.0f : 0.0f;
        }
    }
}

// ---------------- EXPAND: 4 elements/thread, float4 stores (validated r4) ----------------
__global__ __launch_bounds__(256)
void expand_kernel(const uint32_t* __restrict__ packed, float4* __restrict__ out4) {
    int tid = blockIdx.x * blockDim.x + threadIdx.x;
    int base = tid * 4;
    int w0 = (int)((unsigned)base / 27u);
    int pos0 = base - w0 * 27;
    uint32_t a = packed[w0];
    int w1 = w0 + 1; if (w1 > NWORDS - 1) w1 = NWORDS - 1;
    uint32_t b = packed[w1];
    float r[4];
    #pragma unroll
    for (int k = 0; k < 4; ++k) {
        int pp = pos0 + k;
        uint32_t word = (pp < 27) ? a : b;
        int sh = (pp < 27) ? pp : pp - 27;
        r[k] = (float)((word >> sh) & 1u);
    }
    out4[tid] = make_float4(r[0], r[1], r[2], r[3]);
}

extern "C" void kernel_launch(void* const* d_in, const int* in_sizes, int n_in,
                              void* d_out, int out_size, void* d_ws, size_t ws_size,
                              hipStream_t stream) {
    const uint32_t* in = (const uint32_t*)d_in[0];   // float32 bits; nonzero <=> 1.0f
    float* out = (float*)d_out;
    float* solved = out + (size_t)NB * 729;
    uint32_t* packed = (uint32_t*)d_ws;              // NWORDS words = 3.54 MB

    pack_kernel<<<NWORDS / 256, 256, 0, stream>>>(in, packed);          // 3456 blocks
    // solve reads then overwrites its own 27 words: safe in-place
    solve_kernel<<<NB / 64, 192, 0, stream>>>(packed, packed, solved);  // 512 blocks x 192
    expand_kernel<<<(NB * 729 / 4) / 256, 256, 0, stream>>>(packed, (float4*)out); // 23328 blocks
}